// Round 6
// baseline (2967.772 us; speedup 1.0000x reference)
//
#include <hip/hip_runtime.h>
#include <hip/hip_bf16.h>

// krignn2: out = C_qk @ inv(C_kk) @ (VALUE*mlp_v(VALUE))
// C_kk = exp(-cdist(Ks,Ks)) + 1e-3 I,  Ks = KEY*mlp(KEY), Qs = QUERY*mlp(QUERY).
// Blocked fp32 Cholesky (LDL panels) + block-substitution solve.
// R6: k_trtri rewritten blocked — R5's column-serial substitution was a
//     latency-bound dependent LDS chain (8192 iters x ~100cyc = 358us measured).
//     New: 4 parallel register-unrolled 32x32 diag inversions (LDS broadcasts)
//     + 6 GEMM-shaped in-place off-diag steps. Predicted ~25us.

__device__ __forceinline__ int row_of(int e) {
    int i = (int)((sqrtf(8.0f * (float)e + 1.0f) - 1.0f) * 0.5f);
    while ((i + 1) * (i + 2) / 2 <= e) i++;
    while (i * (i + 1) / 2 > e) i--;
    return i;
}

// ---------------- transpose W2 / Wv2 (for coalesced layer-2 reads) -------------
__global__ void k_transpose(const float* __restrict__ W2, const float* __restrict__ Wv2,
                            float* __restrict__ W2T, float* __restrict__ Wv2T) {
    int tid = blockIdx.x * 256 + threadIdx.x;   // 0..32767
    int e = tid & 16383;
    int r = e >> 7, c = e & 127;
    if (tid < 16384) W2T[c * 128 + r] = W2[e];
    else             Wv2T[c * 128 + r] = Wv2[e];
}

// ---------------- MLP (Linear->ReLU->Linear->ReLU->Linear) + elementwise scale --
template<int DI, int P>
__global__ void k_mlp(const float* __restrict__ in, const float* __restrict__ W1,
                      const float* __restrict__ b1, const float* __restrict__ W2T,
                      const float* __restrict__ b2, const float* __restrict__ W3,
                      const float* __restrict__ b3, float* __restrict__ out) {
    __shared__ float xs[P][DI];
    __shared__ float h1[P][128];
    __shared__ float h2[P][129];
    int t = threadIdx.x;
    int base = blockIdx.x * P;
    for (int i = t; i < P * DI; i += 128) xs[i / DI][i % DI] = in[base * DI + i];
    __syncthreads();
    float w1r[DI];
#pragma unroll
    for (int d = 0; d < DI; d++) w1r[d] = W1[t * DI + d];
    float b1t = b1[t], b2t = b2[t];
#pragma unroll
    for (int p = 0; p < P; p++) {
        float s = b1t;
#pragma unroll
        for (int d = 0; d < DI; d++) s += w1r[d] * xs[p][d];
        h1[p][t] = fmaxf(s, 0.0f);
    }
    __syncthreads();
    float acc[P];
#pragma unroll
    for (int p = 0; p < P; p++) acc[p] = b2t;
    for (int k = 0; k < 128; k++) {
        float w = W2T[k * 128 + t];
#pragma unroll
        for (int p = 0; p < P; p++) acc[p] += w * h1[p][k];
    }
#pragma unroll
    for (int p = 0; p < P; p++) h2[p][t] = fmaxf(acc[p], 0.0f);
    __syncthreads();
    if (t < P * DI) {
        int p = t / DI, d = t % DI;
        float s = b3[d];
        for (int k = 0; k < 128; k++) s += W3[d * 128 + k] * h2[p][k];
        int gi = base * DI + t;
        out[gi] = in[gi] * s;
    }
}

// ---------------- build C_kk = exp(-dist) + nugget*I ---------------------------
__global__ void k_buildC(const float* __restrict__ Ks, float* __restrict__ C) {
    long idx = (long)blockIdx.x * 256 + threadIdx.x;  // 16M elements
    int b = (int)(idx >> 20);
    int rem = (int)(idx & 1048575);
    int i = rem >> 10, j = rem & 1023;
    const float* a = Ks + ((long)b * 1024 + i) * 3;
    const float* bb = Ks + ((long)b * 1024 + j) * 3;
    float d0 = a[0] - bb[0], d1 = a[1] - bb[1], d2 = a[2] - bb[2];
    float dist = sqrtf(d0 * d0 + d1 * d1 + d2 * d2 + 1e-12f);
    float v = __expf(-dist);
    if (i == j) v += 1e-3f;
    C[idx] = v;
}

// ---------------- diagonal-block factorization (LDL), full tile in LDS ---------
// grid 16 (batch), block 256. Wave-0 shfl panel (8 cols), rank-8 trailing update.
__global__ __launch_bounds__(256) void k_potf(float* __restrict__ C,
                                              float* __restrict__ invdiag, int o) {
    int b = blockIdx.x, tid = threadIdx.x;
    float* A = C + (long)b * 1048576;
    __shared__ float T[128][133];
    __shared__ float cv[128][9];
    __shared__ float cw[128][9];
    __shared__ float rsd[128];
    // load lower triangle, mirror into upper (full symmetric square in LDS)
    {
        int r = tid >> 1, c0 = (tid & 1) * 64;
        const float* src = A + (long)(o + r) * 1024 + o + c0;
#pragma unroll
        for (int k = 0; k < 16; k++) {
            int c = c0 + 4 * k;
            if (c <= r) {
                float4 v = *(const float4*)(src + 4 * k);
                float vv[4] = {v.x, v.y, v.z, v.w};
#pragma unroll
                for (int m = 0; m < 4; m++) {
                    if (c + m <= r) { T[r][c + m] = vv[m]; T[c + m][r] = vv[m]; }
                }
            }
        }
    }
    __syncthreads();
    int lane = tid & 63;
    int rg = tid >> 4;          // rows rg*8 .. rg*8+7
    int cg = tid & 15;          // cols cg + 16*j
    for (int jb = 0; jb < 128; jb += 8) {
        if (tid < 64) {
            // wave-0 LDL panel: columns jb..jb+7, 2 rows per lane, lazy updates
            int r1 = lane, r2 = 64 + lane;
            float v1[8], v2[8], w1[8], w2[8];
#pragma unroll
            for (int q = 0; q < 8; q++) {
                int j = jb + q;
                int jl = j & 63;
                bool hi = (j >= 64);
                float a1 = T[r1][j], a2 = T[r2][j];
#pragma unroll
                for (int p = 0; p < 8; p++) {
                    if (p < q) {
                        float wj = __shfl(hi ? w2[p] : w1[p], jl);
                        a1 -= v1[p] * wj;
                        a2 -= v2[p] * wj;
                    }
                }
                v1[q] = a1; v2[q] = a2;
                float dj = __shfl(hi ? a2 : a1, jl);
                float dinv = 1.0f / dj;
                w1[q] = a1 * dinv; w2[q] = a2 * dinv;
                if ((hi ? r2 : r1) == j) invdiag[b * 1024 + o + j] = rsqrtf(dj);
            }
#pragma unroll
            for (int q = 0; q < 8; q++) {
                T[r1][jb + q] = v1[q];  T[r2][jb + q] = v2[q];
                cv[r1][q] = v1[q];      cv[r2][q] = v2[q];
                cw[r1][q] = w1[q];      cw[r2][q] = w2[q];
            }
        }
        __syncthreads();
        if (jb < 120) {
            // trailing: full square (keeps symmetry; upper garbage never output)
            float va[8][8];
#pragma unroll
            for (int i = 0; i < 8; i++)
#pragma unroll
                for (int p = 0; p < 8; p++) va[i][p] = cv[rg * 8 + i][p];
#pragma unroll
            for (int j = 0; j < 8; j++) {
                int c = cg + 16 * j;
                if (c >= jb + 8) {
                    float wb[8];
#pragma unroll
                    for (int p = 0; p < 8; p++) wb[p] = cw[c][p];
#pragma unroll
                    for (int i = 0; i < 8; i++) {
                        int r = rg * 8 + i;
                        float t = T[r][c];
#pragma unroll
                        for (int p = 0; p < 8; p++) t -= va[i][p] * wb[p];
                        T[r][c] = t;
                    }
                }
            }
        }
        __syncthreads();
    }
    if (tid < 128) rsd[tid] = rsqrtf(T[tid][tid]);
    __syncthreads();
    // writeback lower (LDL -> Cholesky): L[r][c] = v*rsqrt(d_c); diag = sqrt(d)
#pragma unroll
    for (int j = 0; j < 8; j++) {
        int c = cg + 16 * j;
#pragma unroll
        for (int i = 0; i < 8; i++) {
            int r = rg * 8 + i;
            if (c < r)       A[(long)(o + r) * 1024 + o + c] = T[r][c] * rsd[c];
            else if (c == r) A[(long)(o + r) * 1024 + o + c] = sqrtf(T[r][r]);
        }
    }
}

// ---------------- panel TRSM: L21 = A21 * L11^{-T}, rows in registers ----------
// grid (m/64, 16), block 64. Uniform (scalar-friendly) L11 reads, no LDS.
__global__ __launch_bounds__(64) void k_trsm(float* __restrict__ C,
                                             const float* __restrict__ invdiag, int o) {
    int b = blockIdx.y, t = threadIdx.x;
    float* A = C + (long)b * 1048576;
    const float* __restrict__ invd = invdiag + b * 1024 + o;
    const float* __restrict__ L11 = C + (long)b * 1048576 + (long)o * 1024 + o;
    int row = o + 128 + blockIdx.x * 64 + t;
    float* arow = A + (long)row * 1024 + o;
    float r_[128];
#pragma unroll
    for (int k = 0; k < 32; k++) {
        float4 v = *(const float4*)(arow + 4 * k);
        r_[4*k] = v.x; r_[4*k+1] = v.y; r_[4*k+2] = v.z; r_[4*k+3] = v.w;
    }
#pragma unroll
    for (int jb = 0; jb < 128; jb += 8) {
        float vals[8];
#pragma unroll
        for (int q = 0; q < 8; q++) {
            float s = r_[jb + q];
#pragma unroll
            for (int p = 0; p < 8; p++)
                if (p < q) s -= L11[(long)(jb + q) * 1024 + jb + p] * vals[p];
            vals[q] = s * invd[jb + q];
            r_[jb + q] = vals[q];
        }
#pragma unroll
        for (int k = jb + 8; k < 128; k++) {
            const float* lr = L11 + (long)k * 1024 + jb;
            float4 la = *(const float4*)lr;
            float4 lb = *(const float4*)(lr + 4);
            r_[k] -= la.x*vals[0] + la.y*vals[1] + la.z*vals[2] + la.w*vals[3]
                   + lb.x*vals[4] + lb.y*vals[5] + lb.z*vals[6] + lb.w*vals[7];
        }
    }
#pragma unroll
    for (int k = 0; k < 32; k++) {
        float4 v = make_float4(r_[4*k], r_[4*k+1], r_[4*k+2], r_[4*k+3]);
        *(float4*)(arow + 4 * k) = v;
    }
}

// ---------------- SYRK: A22(lower) -= L21 @ L21^T, 128x128 tiles ---------------
// grid (npairs, 16), block 256 (16x16 threads, 8x8 acc each), K=128 in kc=32.
__global__ __launch_bounds__(256) void k_syrk(float* __restrict__ C, int o) {
    int b = blockIdx.y;
    float* A = C + (long)b * 1048576;
    int pair = blockIdx.x;
    int ti = row_of(pair);
    int tj = pair - ti * (ti + 1) / 2;
    int bi = o + 128 + ti * 128, bj = o + 128 + tj * 128;
    __shared__ float As[32][132];
    __shared__ float Bs[32][132];
    int tid = threadIdx.x;
    int tx = tid & 15, ty = tid >> 4;
    float acc[8][8] = {};
    int lr = tid >> 1;                 // load row 0..127
    int lk = (tid & 1) * 16;           // k-half
    for (int kc = 0; kc < 128; kc += 32) {
        {
            const float* src = A + (long)(bi + lr) * 1024 + o + kc + lk;
#pragma unroll
            for (int k4 = 0; k4 < 4; k4++) {
                float4 v = *(const float4*)(src + 4 * k4);
                As[lk + 4*k4    ][lr] = v.x;
                As[lk + 4*k4 + 1][lr] = v.y;
                As[lk + 4*k4 + 2][lr] = v.z;
                As[lk + 4*k4 + 3][lr] = v.w;
            }
            if (bi != bj) {
                const float* sb = A + (long)(bj + lr) * 1024 + o + kc + lk;
#pragma unroll
                for (int k4 = 0; k4 < 4; k4++) {
                    float4 v = *(const float4*)(sb + 4 * k4);
                    Bs[lk + 4*k4    ][lr] = v.x;
                    Bs[lk + 4*k4 + 1][lr] = v.y;
                    Bs[lk + 4*k4 + 2][lr] = v.z;
                    Bs[lk + 4*k4 + 3][lr] = v.w;
                }
            }
        }
        __syncthreads();
        {
            const float (*Bp)[132] = (bi == bj) ? As : Bs;
#pragma unroll
            for (int k = 0; k < 32; k++) {
                float4 a0 = *(const float4*)&As[k][ty * 8];
                float4 a1 = *(const float4*)&As[k][ty * 8 + 4];
                float4 b0 = *(const float4*)&Bp[k][tx * 8];
                float4 b1 = *(const float4*)&Bp[k][tx * 8 + 4];
                float aa[8] = {a0.x,a0.y,a0.z,a0.w,a1.x,a1.y,a1.z,a1.w};
                float bb[8] = {b0.x,b0.y,b0.z,b0.w,b1.x,b1.y,b1.z,b1.w};
#pragma unroll
                for (int i = 0; i < 8; i++)
#pragma unroll
                    for (int j = 0; j < 8; j++) acc[i][j] += aa[i] * bb[j];
            }
        }
        __syncthreads();
    }
#pragma unroll
    for (int i = 0; i < 8; i++) {
        int r = bi + ty * 8 + i;
        float* dst = A + (long)r * 1024 + bj + tx * 8;
        if (bi != bj) {
            float4 p0 = *(const float4*)dst;
            float4 p1 = *(const float4*)(dst + 4);
            p0.x -= acc[i][0]; p0.y -= acc[i][1]; p0.z -= acc[i][2]; p0.w -= acc[i][3];
            p1.x -= acc[i][4]; p1.y -= acc[i][5]; p1.z -= acc[i][6]; p1.w -= acc[i][7];
            *(float4*)dst = p0;
            *(float4*)(dst + 4) = p1;
        } else {
#pragma unroll
            for (int j = 0; j < 8; j++) {
                int c = bj + tx * 8 + j;
                if (c <= r) dst[j] -= acc[i][j];
            }
        }
    }
}

// ---------------- TRTRI: invert each 128x128 diagonal L block IN PLACE ---------
// grid (8, 16), block 256. Blocked: 4 waves invert the four 32x32 diagonal
// sub-blocks in parallel (register-unrolled, LDS-broadcast reads — no serial
// LDS chain), then 6 in-place GEMM steps for the off-diagonal sub-blocks
// (column-major order makes in-place legal: step (j,i) reads only columns >j
// of original L and already-final column j). Upper triangle written as zeros
// (k_fwd/k_bwd run full-K loops).
__global__ __launch_bounds__(256) void k_trtri(float* __restrict__ C) {
    int ib = blockIdx.x, b = blockIdx.y;
    float* A = C + (long)b * 1048576 + (long)ib * 128 * 1024 + ib * 128;
    __shared__ float T[128][132];   // padded: col accesses spread banks
    __shared__ float W[32][33];
    int tid = threadIdx.x;
    int lane = tid & 63, wv = tid >> 6;
    // load full 128x128 square (upper garbage never read as operand)
    {
        int r = tid >> 1, c0 = (tid & 1) * 64;
        const float* src = A + (long)r * 1024 + c0;
#pragma unroll
        for (int k = 0; k < 16; k++) {
            float4 v = *(const float4*)(src + 4 * k);
            T[r][c0 + 4*k    ] = v.x;
            T[r][c0 + 4*k + 1] = v.y;
            T[r][c0 + 4*k + 2] = v.z;
            T[r][c0 + 4*k + 3] = v.w;
        }
    }
    __syncthreads();
    // phase 2: wave wv inverts diagonal 32x32 sub-block wv (lanes 0..31 = cols)
    if (lane < 32) {
        int d0 = wv * 32;
        int j = lane;
        float x[32];
#pragma unroll
        for (int i = 0; i < 32; i++) {
            float dinv = 1.0f / T[d0 + i][d0 + i];       // LDS broadcast
            float s = 0.0f;
#pragma unroll
            for (int k = 0; k < i; k++) s += T[d0 + i][d0 + k] * x[k];  // broadcast
            x[i] = (i == j) ? dinv : -s * dinv;          // x[i<j] stays exactly 0
        }
#pragma unroll
        for (int i = 0; i < 32; i++) T[d0 + i][d0 + j] = x[i];
    }
    __syncthreads();
    // phase 3: off-diagonal sub-blocks, column-major in-place order
    int orr = tid >> 3;               // output row 0..31
    int oc = (tid & 7) * 4;           // output cols oc..oc+3
    for (int j = 0; j < 3; j++) {
        for (int i = j + 1; i < 4; i++) {
            // W = sum_{k=j}^{i-1} L_ik @ X_kj  (L_ik original for k>j; k=j is L_ij)
            float w0 = 0, w1 = 0, w2 = 0, w3 = 0;
            for (int kb = j; kb < i; kb++) {
#pragma unroll 8
                for (int kk = 0; kk < 32; kk++) {
                    float l = T[i * 32 + orr][kb * 32 + kk];
                    w0 += l * T[kb * 32 + kk][j * 32 + oc    ];
                    w1 += l * T[kb * 32 + kk][j * 32 + oc + 1];
                    w2 += l * T[kb * 32 + kk][j * 32 + oc + 2];
                    w3 += l * T[kb * 32 + kk][j * 32 + oc + 3];
                }
            }
            if (tid < 256) { W[orr][oc] = w0; W[orr][oc+1] = w1; W[orr][oc+2] = w2; W[orr][oc+3] = w3; }
            __syncthreads();
            // X_ij = -Tinv_ii @ W
            float v0 = 0, v1 = 0, v2 = 0, v3 = 0;
#pragma unroll 8
            for (int kk = 0; kk < 32; kk++) {
                float l = T[i * 32 + orr][i * 32 + kk];
                v0 += l * W[kk][oc    ];
                v1 += l * W[kk][oc + 1];
                v2 += l * W[kk][oc + 2];
                v3 += l * W[kk][oc + 3];
            }
            __syncthreads();
            T[i * 32 + orr][j * 32 + oc    ] = -v0;
            T[i * 32 + orr][j * 32 + oc + 1] = -v1;
            T[i * 32 + orr][j * 32 + oc + 2] = -v2;
            T[i * 32 + orr][j * 32 + oc + 3] = -v3;
            __syncthreads();
        }
    }
    // writeback: lower = Linv, upper = 0
    {
        int r = tid >> 1, c0 = (tid & 1) * 64;
        float* dst = A + (long)r * 1024 + c0;
#pragma unroll
        for (int k = 0; k < 4; k++) {
            float4 v;
            int c = c0 + 4 * k * 4;   // process 16 cols as 4x float4
            (void)c;
        }
#pragma unroll
        for (int k = 0; k < 16; k++) {
            int c = c0 + 4 * k;
            float4 v;
            v.x = (c     > r) ? 0.0f : T[r][c    ];
            v.y = (c + 1 > r) ? 0.0f : T[r][c + 1];
            v.z = (c + 2 > r) ? 0.0f : T[r][c + 2];
            v.w = (c + 3 > r) ? 0.0f : T[r][c + 3];
            *(float4*)(dst + 4 * k) = v;
        }
    }
}

// ---------------- forward block substitution: Y = L^{-1} V (8 RHS) -------------
// grid 16 (batch), block 1024 (thread = (row r, rhs c)). Y cached in LDS,
// L blocks staged cooperatively. 8 GEMM-shaped steps, no serial shfl chains.
__global__ __launch_bounds__(1024) void k_fwd(const float* __restrict__ C,
                                              float* __restrict__ V) {
    int b = blockIdx.x;
    const float* A = C + (long)b * 1048576;
    int t = threadIdx.x, c = t >> 7, r = t & 127;
    __shared__ float Lb[128][129];
    __shared__ float Yv[1024][9];
    __shared__ float zb[128][9];
    for (int m = 0; m < 8; m++) {
        int e = t + m * 1024;
        Yv[e >> 3][e & 7] = V[(long)b * 8192 + e];
    }
    __syncthreads();
    for (int i = 0; i < 8; i++) {
        float s = Yv[i * 128 + r][c];
        for (int j = 0; j < i; j++) {
#pragma unroll
            for (int m = 0; m < 16; m++) {
                int e = t + m * 1024;
                Lb[e >> 7][e & 127] = A[(long)(i * 128 + (e >> 7)) * 1024 + j * 128 + (e & 127)];
            }
            __syncthreads();
            float acc = 0.0f;
#pragma unroll 8
            for (int k = 0; k < 128; k++) acc += Lb[r][k] * Yv[j * 128 + k][c];
            s -= acc;
            __syncthreads();
        }
        zb[r][c] = s;
#pragma unroll
        for (int m = 0; m < 16; m++) {
            int e = t + m * 1024;
            Lb[e >> 7][e & 127] = A[(long)(i * 128 + (e >> 7)) * 1024 + i * 128 + (e & 127)];
        }
        __syncthreads();
        float y = 0.0f;
#pragma unroll 8
        for (int k = 0; k < 128; k++) y += Lb[r][k] * zb[k][c];   // Linv_ii @ z
        Yv[i * 128 + r][c] = y;
        __syncthreads();
    }
    for (int m = 0; m < 8; m++) {
        int e = t + m * 1024;
        V[(long)b * 8192 + e] = Yv[e >> 3][e & 7];
    }
}

// ---------------- backward block substitution: X = L^{-T} Y (8 RHS) ------------
__global__ __launch_bounds__(1024) void k_bwd(const float* __restrict__ C,
                                              float* __restrict__ V) {
    int b = blockIdx.x;
    const float* A = C + (long)b * 1048576;
    int t = threadIdx.x, c = t >> 7, r = t & 127;
    __shared__ float Lb[128][129];
    __shared__ float Yv[1024][9];
    __shared__ float zb[128][9];
    for (int m = 0; m < 8; m++) {
        int e = t + m * 1024;
        Yv[e >> 3][e & 7] = V[(long)b * 8192 + e];
    }
    __syncthreads();
    for (int i = 7; i >= 0; i--) {
        float s = Yv[i * 128 + r][c];
        for (int j = i + 1; j < 8; j++) {
            // stage L_ji (block rows j, cols i): Lb[k][r'] = L[j*128+k][i*128+r']
#pragma unroll
            for (int m = 0; m < 16; m++) {
                int e = t + m * 1024;
                Lb[e >> 7][e & 127] = A[(long)(j * 128 + (e >> 7)) * 1024 + i * 128 + (e & 127)];
            }
            __syncthreads();
            float acc = 0.0f;
#pragma unroll 8
            for (int k = 0; k < 128; k++) acc += Lb[k][r] * Yv[j * 128 + k][c];  // L_ji^T
            s -= acc;
            __syncthreads();
        }
        zb[r][c] = s;
#pragma unroll
        for (int m = 0; m < 16; m++) {
            int e = t + m * 1024;
            Lb[e >> 7][e & 127] = A[(long)(i * 128 + (e >> 7)) * 1024 + i * 128 + (e & 127)];
        }
        __syncthreads();
        float y = 0.0f;
#pragma unroll 8
        for (int k = 0; k < 128; k++) y += Lb[k][r] * zb[k][c];   // Linv_ii^T @ z
        Yv[i * 128 + r][c] = y;
        __syncthreads();
    }
    for (int m = 0; m < 8; m++) {
        int e = t + m * 1024;
        V[(long)b * 8192 + e] = Yv[e >> 3][e & 7];
    }
}

// ---------------- fused output: out[q,:] = sum_k exp(-d(Qs_q,Ks_k)) X[k,:] -----
// grid 256 (16 batch x 16 query-chunks), block 256 (64 queries x 4 k-subsets).
__global__ void k_out(const float* __restrict__ Qs, const float* __restrict__ Ks,
                      const float* __restrict__ X, float* __restrict__ out) {
    int b = blockIdx.x >> 4;
    int qc = blockIdx.x & 15;
    int t = threadIdx.x;
    int q = t & 63, ks = t >> 6;
    __shared__ float kx[1024][3];
    __shared__ __align__(16) float xv[1024][8];
    __shared__ float red[4][64][8];
    for (int i = t; i < 3072; i += 256) kx[i / 3][i % 3] = Ks[b * 3072 + i];
    for (int i = t; i < 8192; i += 256) xv[i >> 3][i & 7] = X[b * 8192 + i];
    __syncthreads();
    int gq = b * 1024 + qc * 64 + q;
    const float* qp = Qs + (long)gq * 3;
    float qx = qp[0], qy = qp[1], qz = qp[2];
    float acc[8] = {};
    int k0 = ks * 256;
#pragma unroll 2
    for (int k = k0; k < k0 + 256; k++) {
        float dx = qx - kx[k][0], dy = qy - kx[k][1], dz = qz - kx[k][2];
        float w = __expf(-sqrtf(dx * dx + dy * dy + dz * dz + 1e-12f));
        float4 xa = *(const float4*)&xv[k][0];
        float4 xb = *(const float4*)&xv[k][4];
        acc[0] += w * xa.x; acc[1] += w * xa.y; acc[2] += w * xa.z; acc[3] += w * xa.w;
        acc[4] += w * xb.x; acc[5] += w * xb.y; acc[6] += w * xb.z; acc[7] += w * xb.w;
    }
#pragma unroll
    for (int c = 0; c < 8; c++) red[ks][q][c] = acc[c];
    __syncthreads();
    if (ks == 0) {
        float* op = out + (long)gq * 8;
#pragma unroll
        for (int c = 0; c < 8; c++)
            op[c] = red[0][q][c] + red[1][q][c] + red[2][q][c] + red[3][q][c];
    }
}

extern "C" void kernel_launch(void* const* d_in, const int* in_sizes, int n_in,
                              void* d_out, int out_size, void* d_ws, size_t ws_size,
                              hipStream_t stream) {
    const float* KEY   = (const float*)d_in[0];
    const float* VALUE = (const float*)d_in[1];
    const float* QUERY = (const float*)d_in[2];
    const float* W1w = (const float*)d_in[3];  const float* W1b = (const float*)d_in[4];
    const float* W2w = (const float*)d_in[5];  const float* W2b = (const float*)d_in[6];
    const float* W3w = (const float*)d_in[7];  const float* W3b = (const float*)d_in[8];
    const float* Wv1w = (const float*)d_in[9]; const float* Wv1b = (const float*)d_in[10];
    const float* Wv2w = (const float*)d_in[11];const float* Wv2b = (const float*)d_in[12];
    const float* Wv3w = (const float*)d_in[13];const float* Wv3b = (const float*)d_in[14];

    float* ws  = (float*)d_ws;
    float* C    = ws;                 // 16*1024*1024
    float* Ks   = C + 16777216;       // 16*1024*3
    float* Qs   = Ks + 49152;
    float* Vs   = Qs + 49152;         // 16*1024*8 (becomes X in place)
    float* W2T  = Vs + 131072;
    float* Wv2T = W2T + 16384;
    float* invd = Wv2T + 16384;       // 16*1024

    float* out = (float*)d_out;

    hipLaunchKernelGGL(k_transpose, dim3(128), dim3(256), 0, stream, W2w, Wv2w, W2T, Wv2T);
    hipLaunchKernelGGL((k_mlp<3, 32>), dim3(512), dim3(128), 0, stream,
                       KEY, W1w, W1b, W2T, W2b, W3w, W3b, Ks);
    hipLaunchKernelGGL((k_mlp<3, 32>), dim3(512), dim3(128), 0, stream,
                       QUERY, W1w, W1b, W2T, W2b, W3w, W3b, Qs);
    hipLaunchKernelGGL((k_mlp<8, 16>), dim3(1024), dim3(128), 0, stream,
                       VALUE, Wv1w, Wv1b, Wv2T, Wv2b, Wv3w, Wv3b, Vs);
    hipLaunchKernelGGL(k_buildC, dim3(65536), dim3(256), 0, stream, Ks, C);

    for (int s = 0; s < 8; s++) {
        int o = s * 128;
        hipLaunchKernelGGL(k_potf, dim3(16), dim3(256), 0, stream, C, invd, o);
        int m = 1024 - o - 128;
        if (m > 0) {
            hipLaunchKernelGGL(k_trsm, dim3(m / 64, 16), dim3(64), 0, stream, C, invd, o);
            int nt = m / 128;
            int np = nt * (nt + 1) / 2;
            hipLaunchKernelGGL(k_syrk, dim3(np, 16), dim3(256), 0, stream, C, o);
        }
    }
    hipLaunchKernelGGL(k_trtri, dim3(8, 16), dim3(256), 0, stream, C);
    hipLaunchKernelGGL(k_fwd, dim3(16), dim3(1024), 0, stream, C, Vs);
    hipLaunchKernelGGL(k_bwd, dim3(16), dim3(1024), 0, stream, C, Vs);
    hipLaunchKernelGGL(k_out, dim3(256), dim3(256), 0, stream, Qs, Ks, Vs, out);
}

// Round 7
// 1482.499 us; speedup vs baseline: 2.0019x; 2.0019x over previous
//
#include <hip/hip_runtime.h>
#include <hip/hip_bf16.h>

// krignn2: out = C_qk @ inv(C_kk) @ (VALUE*mlp_v(VALUE))
// C_kk = exp(-cdist(Ks,Ks)) + 1e-3 I,  Ks = KEY*mlp(KEY), Qs = QUERY*mlp(QUERY).
// Blocked fp32 Cholesky + block-substitution solve with inverted diag blocks.
// R7: TRSM -> TRTRI+GEMM. R6's k_trsm (1-wave WGs, dependent uniform L11 loads)
//     was latency-bound at ~265us x7 = 65% of runtime. Nothing needs L_ii itself,
//     so k_potf now fuses the blocked inversion (R6 k_trtri phases) and writes
//     Linv_ii directly; k_trsmg computes L21 = A21 @ Linv^T as a syrk-shaped
//     GEMM (128x128 tiles, 8x8 acc, K=128 in LDS). ~1.9 GFLOP total ≈ 50us.

__device__ __forceinline__ int row_of(int e) {
    int i = (int)((sqrtf(8.0f * (float)e + 1.0f) - 1.0f) * 0.5f);
    while ((i + 1) * (i + 2) / 2 <= e) i++;
    while (i * (i + 1) / 2 > e) i--;
    return i;
}

// ---------------- transpose W2 / Wv2 (for coalesced layer-2 reads) -------------
__global__ void k_transpose(const float* __restrict__ W2, const float* __restrict__ Wv2,
                            float* __restrict__ W2T, float* __restrict__ Wv2T) {
    int tid = blockIdx.x * 256 + threadIdx.x;   // 0..32767
    int e = tid & 16383;
    int r = e >> 7, c = e & 127;
    if (tid < 16384) W2T[c * 128 + r] = W2[e];
    else             Wv2T[c * 128 + r] = Wv2[e];
}

// ---------------- MLP (Linear->ReLU->Linear->ReLU->Linear) + elementwise scale --
template<int DI, int P>
__global__ void k_mlp(const float* __restrict__ in, const float* __restrict__ W1,
                      const float* __restrict__ b1, const float* __restrict__ W2T,
                      const float* __restrict__ b2, const float* __restrict__ W3,
                      const float* __restrict__ b3, float* __restrict__ out) {
    __shared__ float xs[P][DI];
    __shared__ float h1[P][128];
    __shared__ float h2[P][129];
    int t = threadIdx.x;
    int base = blockIdx.x * P;
    for (int i = t; i < P * DI; i += 128) xs[i / DI][i % DI] = in[base * DI + i];
    __syncthreads();
    float w1r[DI];
#pragma unroll
    for (int d = 0; d < DI; d++) w1r[d] = W1[t * DI + d];
    float b1t = b1[t], b2t = b2[t];
#pragma unroll
    for (int p = 0; p < P; p++) {
        float s = b1t;
#pragma unroll
        for (int d = 0; d < DI; d++) s += w1r[d] * xs[p][d];
        h1[p][t] = fmaxf(s, 0.0f);
    }
    __syncthreads();
    float acc[P];
#pragma unroll
    for (int p = 0; p < P; p++) acc[p] = b2t;
    for (int k = 0; k < 128; k++) {
        float w = W2T[k * 128 + t];
#pragma unroll
        for (int p = 0; p < P; p++) acc[p] += w * h1[p][k];
    }
#pragma unroll
    for (int p = 0; p < P; p++) h2[p][t] = fmaxf(acc[p], 0.0f);
    __syncthreads();
    if (t < P * DI) {
        int p = t / DI, d = t % DI;
        float s = b3[d];
        for (int k = 0; k < 128; k++) s += W3[d * 128 + k] * h2[p][k];
        int gi = base * DI + t;
        out[gi] = in[gi] * s;
    }
}

// ---------------- build C_kk = exp(-dist) + nugget*I ---------------------------
__global__ void k_buildC(const float* __restrict__ Ks, float* __restrict__ C) {
    long idx = (long)blockIdx.x * 256 + threadIdx.x;  // 16M elements
    int b = (int)(idx >> 20);
    int rem = (int)(idx & 1048575);
    int i = rem >> 10, j = rem & 1023;
    const float* a = Ks + ((long)b * 1024 + i) * 3;
    const float* bb = Ks + ((long)b * 1024 + j) * 3;
    float d0 = a[0] - bb[0], d1 = a[1] - bb[1], d2 = a[2] - bb[2];
    float dist = sqrtf(d0 * d0 + d1 * d1 + d2 * d2 + 1e-12f);
    float v = __expf(-dist);
    if (i == j) v += 1e-3f;
    C[idx] = v;
}

// ---------------- potf+trtri: factor diag block, write Linv_ii IN PLACE --------
// grid 16 (batch), block 256. LDL panels (wave-0 shfl), convert to Cholesky in
// LDS, then blocked inversion (4 parallel 32x32 wave-inversions + 6 GEMM steps).
// Output: full 128x128 Linv_ii with zeros above diagonal.
__global__ __launch_bounds__(256) void k_potf(float* __restrict__ C, int o) {
    int b = blockIdx.x, tid = threadIdx.x;
    float* A = C + (long)b * 1048576;
    __shared__ float T[128][133];
    __shared__ float cv[128][9];
    __shared__ float cw[128][9];
    __shared__ float rsd[128];
    __shared__ float W[32][33];
    // load lower triangle, mirror into upper (full symmetric square in LDS)
    {
        int r = tid >> 1, c0 = (tid & 1) * 64;
        const float* src = A + (long)(o + r) * 1024 + o + c0;
#pragma unroll
        for (int k = 0; k < 16; k++) {
            int c = c0 + 4 * k;
            if (c <= r) {
                float4 v = *(const float4*)(src + 4 * k);
                float vv[4] = {v.x, v.y, v.z, v.w};
#pragma unroll
                for (int m = 0; m < 4; m++) {
                    if (c + m <= r) { T[r][c + m] = vv[m]; T[c + m][r] = vv[m]; }
                }
            }
        }
    }
    __syncthreads();
    int lane = tid & 63, wv = tid >> 6;
    int rg = tid >> 4;          // rows rg*8 .. rg*8+7
    int cg = tid & 15;          // cols cg + 16*j
    // ---- LDL factorization, rank-8 panels ----
    for (int jb = 0; jb < 128; jb += 8) {
        if (tid < 64) {
            int r1 = lane, r2 = 64 + lane;
            float v1[8], v2[8], w1[8], w2[8];
#pragma unroll
            for (int q = 0; q < 8; q++) {
                int j = jb + q;
                int jl = j & 63;
                bool hi = (j >= 64);
                float a1 = T[r1][j], a2 = T[r2][j];
#pragma unroll
                for (int p = 0; p < 8; p++) {
                    if (p < q) {
                        float wj = __shfl(hi ? w2[p] : w1[p], jl);
                        a1 -= v1[p] * wj;
                        a2 -= v2[p] * wj;
                    }
                }
                v1[q] = a1; v2[q] = a2;
                float dj = __shfl(hi ? a2 : a1, jl);
                float dinv = 1.0f / dj;
                w1[q] = a1 * dinv; w2[q] = a2 * dinv;
            }
#pragma unroll
            for (int q = 0; q < 8; q++) {
                T[r1][jb + q] = v1[q];  T[r2][jb + q] = v2[q];
                cv[r1][q] = v1[q];      cv[r2][q] = v2[q];
                cw[r1][q] = w1[q];      cw[r2][q] = w2[q];
            }
        }
        __syncthreads();
        if (jb < 120) {
            float va[8][8];
#pragma unroll
            for (int i = 0; i < 8; i++)
#pragma unroll
                for (int p = 0; p < 8; p++) va[i][p] = cv[rg * 8 + i][p];
#pragma unroll
            for (int j = 0; j < 8; j++) {
                int c = cg + 16 * j;
                if (c >= jb + 8) {
                    float wb[8];
#pragma unroll
                    for (int p = 0; p < 8; p++) wb[p] = cw[c][p];
#pragma unroll
                    for (int i = 0; i < 8; i++) {
                        int r = rg * 8 + i;
                        float t = T[r][c];
#pragma unroll
                        for (int p = 0; p < 8; p++) t -= va[i][p] * wb[p];
                        T[r][c] = t;
                    }
                }
            }
        }
        __syncthreads();
    }
    // ---- convert LDL -> Cholesky L in LDS (lower incl diag; upper garbage) ----
    if (tid < 128) rsd[tid] = rsqrtf(T[tid][tid]);
    __syncthreads();
#pragma unroll
    for (int j = 0; j < 8; j++) {
        int c = cg + 16 * j;
#pragma unroll
        for (int i = 0; i < 8; i++) {
            int r = rg * 8 + i;
            if (c <= r) T[r][c] *= rsd[c];    // diag: d*rsqrt(d) = sqrt(d)
        }
    }
    __syncthreads();
    // ---- trtri phase 2: 4 waves invert the 32x32 diagonal sub-blocks ----
    if (lane < 32) {
        int d0 = wv * 32;
        int j = lane;
        float x[32];
#pragma unroll
        for (int i = 0; i < 32; i++) {
            float dinv = 1.0f / T[d0 + i][d0 + i];       // LDS broadcast
            float s = 0.0f;
#pragma unroll
            for (int k = 0; k < i; k++) s += T[d0 + i][d0 + k] * x[k];
            x[i] = (i == j) ? dinv : -s * dinv;          // x[i<j] stays exactly 0
        }
#pragma unroll
        for (int i = 0; i < 32; i++) T[d0 + i][d0 + j] = x[i];
    }
    __syncthreads();
    // ---- trtri phase 3: off-diagonal sub-blocks, column-major in-place ----
    int orr = tid >> 3;               // output row 0..31
    int oc = (tid & 7) * 4;           // output cols oc..oc+3
    for (int j = 0; j < 3; j++) {
        for (int i = j + 1; i < 4; i++) {
            float w0 = 0, w1 = 0, w2 = 0, w3 = 0;
            for (int kb = j; kb < i; kb++) {
#pragma unroll 8
                for (int kk = 0; kk < 32; kk++) {
                    float l = T[i * 32 + orr][kb * 32 + kk];
                    w0 += l * T[kb * 32 + kk][j * 32 + oc    ];
                    w1 += l * T[kb * 32 + kk][j * 32 + oc + 1];
                    w2 += l * T[kb * 32 + kk][j * 32 + oc + 2];
                    w3 += l * T[kb * 32 + kk][j * 32 + oc + 3];
                }
            }
            W[orr][oc] = w0; W[orr][oc+1] = w1; W[orr][oc+2] = w2; W[orr][oc+3] = w3;
            __syncthreads();
            float v0 = 0, v1 = 0, v2 = 0, v3 = 0;
#pragma unroll 8
            for (int kk = 0; kk < 32; kk++) {
                float l = T[i * 32 + orr][i * 32 + kk];
                v0 += l * W[kk][oc    ];
                v1 += l * W[kk][oc + 1];
                v2 += l * W[kk][oc + 2];
                v3 += l * W[kk][oc + 3];
            }
            __syncthreads();
            T[i * 32 + orr][j * 32 + oc    ] = -v0;
            T[i * 32 + orr][j * 32 + oc + 1] = -v1;
            T[i * 32 + orr][j * 32 + oc + 2] = -v2;
            T[i * 32 + orr][j * 32 + oc + 3] = -v3;
            __syncthreads();
        }
    }
    // ---- writeback: lower = Linv_ii, upper = 0 ----
    {
        int r = tid >> 1, c0 = (tid & 1) * 64;
        float* dst = A + (long)(o + r) * 1024 + o + c0;
#pragma unroll
        for (int k = 0; k < 16; k++) {
            int c = c0 + 4 * k;
            float4 v;
            v.x = (c     > r) ? 0.0f : T[r][c    ];
            v.y = (c + 1 > r) ? 0.0f : T[r][c + 1];
            v.z = (c + 2 > r) ? 0.0f : T[r][c + 2];
            v.w = (c + 3 > r) ? 0.0f : T[r][c + 3];
            *(float4*)(dst + 4 * k) = v;
        }
    }
}

// ---------------- TRSM as GEMM: L21 = A21 @ Linv_ii^T --------------------------
// grid (m/128, 16), block 256 (16x16, 8x8 acc). Same structure as k_syrk.
__global__ __launch_bounds__(256) void k_trsmg(float* __restrict__ C, int o) {
    int b = blockIdx.y;
    float* A = C + (long)b * 1048576;
    int bi = o + 128 + blockIdx.x * 128;
    const float* Linv = A + (long)o * 1024 + o;   // stride 1024
    __shared__ float As[32][132];
    __shared__ float Ls[32][132];
    int tid = threadIdx.x;
    int tx = tid & 15, ty = tid >> 4;
    float acc[8][8] = {};
    int lr = tid >> 1;                 // row 0..127
    int lk = (tid & 1) * 16;           // k-half
    for (int kc = 0; kc < 128; kc += 32) {
        const float* src = A + (long)(bi + lr) * 1024 + o + kc + lk;
        const float* sl  = Linv + (long)lr * 1024 + kc + lk;
#pragma unroll
        for (int k4 = 0; k4 < 4; k4++) {
            float4 v = *(const float4*)(src + 4 * k4);
            As[lk + 4*k4    ][lr] = v.x;
            As[lk + 4*k4 + 1][lr] = v.y;
            As[lk + 4*k4 + 2][lr] = v.z;
            As[lk + 4*k4 + 3][lr] = v.w;
            float4 w = *(const float4*)(sl + 4 * k4);
            Ls[lk + 4*k4    ][lr] = w.x;
            Ls[lk + 4*k4 + 1][lr] = w.y;
            Ls[lk + 4*k4 + 2][lr] = w.z;
            Ls[lk + 4*k4 + 3][lr] = w.w;
        }
        __syncthreads();
#pragma unroll
        for (int k = 0; k < 32; k++) {
            float4 a0 = *(const float4*)&As[k][ty * 8];
            float4 a1 = *(const float4*)&As[k][ty * 8 + 4];
            float4 b0 = *(const float4*)&Ls[k][tx * 8];
            float4 b1 = *(const float4*)&Ls[k][tx * 8 + 4];
            float aa[8] = {a0.x,a0.y,a0.z,a0.w,a1.x,a1.y,a1.z,a1.w};
            float bb[8] = {b0.x,b0.y,b0.z,b0.w,b1.x,b1.y,b1.z,b1.w};
#pragma unroll
            for (int i = 0; i < 8; i++)
#pragma unroll
                for (int j = 0; j < 8; j++) acc[i][j] += aa[i] * bb[j];
        }
        __syncthreads();
    }
#pragma unroll
    for (int i = 0; i < 8; i++) {
        float* dst = A + (long)(bi + ty * 8 + i) * 1024 + o + tx * 8;
        float4 p0 = make_float4(acc[i][0], acc[i][1], acc[i][2], acc[i][3]);
        float4 p1 = make_float4(acc[i][4], acc[i][5], acc[i][6], acc[i][7]);
        *(float4*)dst = p0;
        *(float4*)(dst + 4) = p1;
    }
}

// ---------------- SYRK: A22(lower) -= L21 @ L21^T, 128x128 tiles ---------------
// grid (npairs, 16), block 256 (16x16 threads, 8x8 acc each), K=128 in kc=32.
__global__ __launch_bounds__(256) void k_syrk(float* __restrict__ C, int o) {
    int b = blockIdx.y;
    float* A = C + (long)b * 1048576;
    int pair = blockIdx.x;
    int ti = row_of(pair);
    int tj = pair - ti * (ti + 1) / 2;
    int bi = o + 128 + ti * 128, bj = o + 128 + tj * 128;
    __shared__ float As[32][132];
    __shared__ float Bs[32][132];
    int tid = threadIdx.x;
    int tx = tid & 15, ty = tid >> 4;
    float acc[8][8] = {};
    int lr = tid >> 1;                 // load row 0..127
    int lk = (tid & 1) * 16;           // k-half
    for (int kc = 0; kc < 128; kc += 32) {
        {
            const float* src = A + (long)(bi + lr) * 1024 + o + kc + lk;
#pragma unroll
            for (int k4 = 0; k4 < 4; k4++) {
                float4 v = *(const float4*)(src + 4 * k4);
                As[lk + 4*k4    ][lr] = v.x;
                As[lk + 4*k4 + 1][lr] = v.y;
                As[lk + 4*k4 + 2][lr] = v.z;
                As[lk + 4*k4 + 3][lr] = v.w;
            }
            if (bi != bj) {
                const float* sb = A + (long)(bj + lr) * 1024 + o + kc + lk;
#pragma unroll
                for (int k4 = 0; k4 < 4; k4++) {
                    float4 v = *(const float4*)(sb + 4 * k4);
                    Bs[lk + 4*k4    ][lr] = v.x;
                    Bs[lk + 4*k4 + 1][lr] = v.y;
                    Bs[lk + 4*k4 + 2][lr] = v.z;
                    Bs[lk + 4*k4 + 3][lr] = v.w;
                }
            }
        }
        __syncthreads();
        {
            const float (*Bp)[132] = (bi == bj) ? As : Bs;
#pragma unroll
            for (int k = 0; k < 32; k++) {
                float4 a0 = *(const float4*)&As[k][ty * 8];
                float4 a1 = *(const float4*)&As[k][ty * 8 + 4];
                float4 b0 = *(const float4*)&Bp[k][tx * 8];
                float4 b1 = *(const float4*)&Bp[k][tx * 8 + 4];
                float aa[8] = {a0.x,a0.y,a0.z,a0.w,a1.x,a1.y,a1.z,a1.w};
                float bb[8] = {b0.x,b0.y,b0.z,b0.w,b1.x,b1.y,b1.z,b1.w};
#pragma unroll
                for (int i = 0; i < 8; i++)
#pragma unroll
                    for (int j = 0; j < 8; j++) acc[i][j] += aa[i] * bb[j];
            }
        }
        __syncthreads();
    }
#pragma unroll
    for (int i = 0; i < 8; i++) {
        int r = bi + ty * 8 + i;
        float* dst = A + (long)r * 1024 + bj + tx * 8;
        if (bi != bj) {
            float4 p0 = *(const float4*)dst;
            float4 p1 = *(const float4*)(dst + 4);
            p0.x -= acc[i][0]; p0.y -= acc[i][1]; p0.z -= acc[i][2]; p0.w -= acc[i][3];
            p1.x -= acc[i][4]; p1.y -= acc[i][5]; p1.z -= acc[i][6]; p1.w -= acc[i][7];
            *(float4*)dst = p0;
            *(float4*)(dst + 4) = p1;
        } else {
#pragma unroll
            for (int j = 0; j < 8; j++) {
                int c = bj + tx * 8 + j;
                if (c <= r) dst[j] -= acc[i][j];
            }
        }
    }
}

// ---------------- forward block substitution: Y = L^{-1} V (8 RHS) -------------
// grid 16 (batch), block 1024 (thread = (row r, rhs c)). Y cached in LDS,
// L blocks staged cooperatively. 8 GEMM-shaped steps, no serial shfl chains.
__global__ __launch_bounds__(1024) void k_fwd(const float* __restrict__ C,
                                              float* __restrict__ V) {
    int b = blockIdx.x;
    const float* A = C + (long)b * 1048576;
    int t = threadIdx.x, c = t >> 7, r = t & 127;
    __shared__ float Lb[128][129];
    __shared__ float Yv[1024][9];
    __shared__ float zb[128][9];
    for (int m = 0; m < 8; m++) {
        int e = t + m * 1024;
        Yv[e >> 3][e & 7] = V[(long)b * 8192 + e];
    }
    __syncthreads();
    for (int i = 0; i < 8; i++) {
        float s = Yv[i * 128 + r][c];
        for (int j = 0; j < i; j++) {
#pragma unroll
            for (int m = 0; m < 16; m++) {
                int e = t + m * 1024;
                Lb[e >> 7][e & 127] = A[(long)(i * 128 + (e >> 7)) * 1024 + j * 128 + (e & 127)];
            }
            __syncthreads();
            float acc = 0.0f;
#pragma unroll 8
            for (int k = 0; k < 128; k++) acc += Lb[r][k] * Yv[j * 128 + k][c];
            s -= acc;
            __syncthreads();
        }
        zb[r][c] = s;
#pragma unroll
        for (int m = 0; m < 16; m++) {
            int e = t + m * 1024;
            Lb[e >> 7][e & 127] = A[(long)(i * 128 + (e >> 7)) * 1024 + i * 128 + (e & 127)];
        }
        __syncthreads();
        float y = 0.0f;
#pragma unroll 8
        for (int k = 0; k < 128; k++) y += Lb[r][k] * zb[k][c];   // Linv_ii @ z
        Yv[i * 128 + r][c] = y;
        __syncthreads();
    }
    for (int m = 0; m < 8; m++) {
        int e = t + m * 1024;
        V[(long)b * 8192 + e] = Yv[e >> 3][e & 7];
    }
}

// ---------------- backward block substitution: X = L^{-T} Y (8 RHS) ------------
__global__ __launch_bounds__(1024) void k_bwd(const float* __restrict__ C,
                                              float* __restrict__ V) {
    int b = blockIdx.x;
    const float* A = C + (long)b * 1048576;
    int t = threadIdx.x, c = t >> 7, r = t & 127;
    __shared__ float Lb[128][129];
    __shared__ float Yv[1024][9];
    __shared__ float zb[128][9];
    for (int m = 0; m < 8; m++) {
        int e = t + m * 1024;
        Yv[e >> 3][e & 7] = V[(long)b * 8192 + e];
    }
    __syncthreads();
    for (int i = 7; i >= 0; i--) {
        float s = Yv[i * 128 + r][c];
        for (int j = i + 1; j < 8; j++) {
            // stage L_ji (block rows j, cols i): Lb[k][r'] = L[j*128+k][i*128+r']
#pragma unroll
            for (int m = 0; m < 16; m++) {
                int e = t + m * 1024;
                Lb[e >> 7][e & 127] = A[(long)(j * 128 + (e >> 7)) * 1024 + i * 128 + (e & 127)];
            }
            __syncthreads();
            float acc = 0.0f;
#pragma unroll 8
            for (int k = 0; k < 128; k++) acc += Lb[k][r] * Yv[j * 128 + k][c];  // L_ji^T
            s -= acc;
            __syncthreads();
        }
        zb[r][c] = s;
#pragma unroll
        for (int m = 0; m < 16; m++) {
            int e = t + m * 1024;
            Lb[e >> 7][e & 127] = A[(long)(i * 128 + (e >> 7)) * 1024 + i * 128 + (e & 127)];
        }
        __syncthreads();
        float y = 0.0f;
#pragma unroll 8
        for (int k = 0; k < 128; k++) y += Lb[k][r] * zb[k][c];   // Linv_ii^T @ z
        Yv[i * 128 + r][c] = y;
        __syncthreads();
    }
    for (int m = 0; m < 8; m++) {
        int e = t + m * 1024;
        V[(long)b * 8192 + e] = Yv[e >> 3][e & 7];
    }
}

// ---------------- fused output: out[q,:] = sum_k exp(-d(Qs_q,Ks_k)) X[k,:] -----
// grid 256 (16 batch x 16 query-chunks), block 256 (64 queries x 4 k-subsets).
__global__ void k_out(const float* __restrict__ Qs, const float* __restrict__ Ks,
                      const float* __restrict__ X, float* __restrict__ out) {
    int b = blockIdx.x >> 4;
    int qc = blockIdx.x & 15;
    int t = threadIdx.x;
    int q = t & 63, ks = t >> 6;
    __shared__ float kx[1024][3];
    __shared__ __align__(16) float xv[1024][8];
    __shared__ float red[4][64][8];
    for (int i = t; i < 3072; i += 256) kx[i / 3][i % 3] = Ks[b * 3072 + i];
    for (int i = t; i < 8192; i += 256) xv[i >> 3][i & 7] = X[b * 8192 + i];
    __syncthreads();
    int gq = b * 1024 + qc * 64 + q;
    const float* qp = Qs + (long)gq * 3;
    float qx = qp[0], qy = qp[1], qz = qp[2];
    float acc[8] = {};
    int k0 = ks * 256;
#pragma unroll 2
    for (int k = k0; k < k0 + 256; k++) {
        float dx = qx - kx[k][0], dy = qy - kx[k][1], dz = qz - kx[k][2];
        float w = __expf(-sqrtf(dx * dx + dy * dy + dz * dz + 1e-12f));
        float4 xa = *(const float4*)&xv[k][0];
        float4 xb = *(const float4*)&xv[k][4];
        acc[0] += w * xa.x; acc[1] += w * xa.y; acc[2] += w * xa.z; acc[3] += w * xa.w;
        acc[4] += w * xb.x; acc[5] += w * xb.y; acc[6] += w * xb.z; acc[7] += w * xb.w;
    }
#pragma unroll
    for (int c = 0; c < 8; c++) red[ks][q][c] = acc[c];
    __syncthreads();
    if (ks == 0) {
        float* op = out + (long)gq * 8;
#pragma unroll
        for (int c = 0; c < 8; c++)
            op[c] = red[0][q][c] + red[1][q][c] + red[2][q][c] + red[3][q][c];
    }
}

extern "C" void kernel_launch(void* const* d_in, const int* in_sizes, int n_in,
                              void* d_out, int out_size, void* d_ws, size_t ws_size,
                              hipStream_t stream) {
    const float* KEY   = (const float*)d_in[0];
    const float* VALUE = (const float*)d_in[1];
    const float* QUERY = (const float*)d_in[2];
    const float* W1w = (const float*)d_in[3];  const float* W1b = (const float*)d_in[4];
    const float* W2w = (const float*)d_in[5];  const float* W2b = (const float*)d_in[6];
    const float* W3w = (const float*)d_in[7];  const float* W3b = (const float*)d_in[8];
    const float* Wv1w = (const float*)d_in[9]; const float* Wv1b = (const float*)d_in[10];
    const float* Wv2w = (const float*)d_in[11];const float* Wv2b = (const float*)d_in[12];
    const float* Wv3w = (const float*)d_in[13];const float* Wv3b = (const float*)d_in[14];

    float* ws  = (float*)d_ws;
    float* C    = ws;                 // 16*1024*1024
    float* Ks   = C + 16777216;       // 16*1024*3
    float* Qs   = Ks + 49152;
    float* Vs   = Qs + 49152;         // 16*1024*8 (becomes X in place)
    float* W2T  = Vs + 131072;
    float* Wv2T = W2T + 16384;

    float* out = (float*)d_out;

    hipLaunchKernelGGL(k_transpose, dim3(128), dim3(256), 0, stream, W2w, Wv2w, W2T, Wv2T);
    hipLaunchKernelGGL((k_mlp<3, 32>), dim3(512), dim3(128), 0, stream,
                       KEY, W1w, W1b, W2T, W2b, W3w, W3b, Ks);
    hipLaunchKernelGGL((k_mlp<3, 32>), dim3(512), dim3(128), 0, stream,
                       QUERY, W1w, W1b, W2T, W2b, W3w, W3b, Qs);
    hipLaunchKernelGGL((k_mlp<8, 16>), dim3(1024), dim3(128), 0, stream,
                       VALUE, Wv1w, Wv1b, Wv2T, Wv2b, Wv3w, Wv3b, Vs);
    hipLaunchKernelGGL(k_buildC, dim3(65536), dim3(256), 0, stream, Ks, C);

    for (int s = 0; s < 8; s++) {
        int o = s * 128;
        hipLaunchKernelGGL(k_potf, dim3(16), dim3(256), 0, stream, C, o);
        int m = 1024 - o - 128;
        if (m > 0) {
            hipLaunchKernelGGL(k_trsmg, dim3(m / 128, 16), dim3(256), 0, stream, C, o);
            int nt = m / 128;
            int np = nt * (nt + 1) / 2;
            hipLaunchKernelGGL(k_syrk, dim3(np, 16), dim3(256), 0, stream, C, o);
        }
    }
    hipLaunchKernelGGL(k_fwd, dim3(16), dim3(1024), 0, stream, C, Vs);
    hipLaunchKernelGGL(k_bwd, dim3(16), dim3(1024), 0, stream, C, Vs);
    hipLaunchKernelGGL(k_out, dim3(256), dim3(256), 0, stream, Qs, Ks, Vs, out);
}